// Round 2
// baseline (396.910 us; speedup 1.0000x reference)
//
#include <hip/hip_runtime.h>
#include <hip/hip_bf16.h>

#define SPA 110592            // D*H*W = 48*48*48
#define NPOS 221184           // B * SPA  (B=2)
#define NELEM 14155776        // B*C*SPA
#define KCODES 256
#define CCH 64
#define DWBLK 432             // 432 * 512 = NPOS exactly
#define DWTHR 512

// ---------------- init: zero accumulators, precompute ||e_k||^2 ----------------
__global__ __launch_bounds__(256) void vq_init(
    const float* __restrict__ emb, float* __restrict__ en2,
    float* __restrict__ dw, float* __restrict__ hist, float* __restrict__ loss)
{
    int t = blockIdx.x * 256 + threadIdx.x;   // 64 blocks -> 16384 threads
    if (t < CCH * KCODES) dw[t] = 0.f;        // needed only for atomic fallback; cheap
    if (t < KCODES) {
        const float* e = emb + (t << 6);
        float s = 0.f;
#pragma unroll
        for (int c = 0; c < CCH; ++c) s = fmaf(e[c], e[c], s);
        en2[t] = s;
        hist[t] = 0.f;
    }
    if (t == 0) loss[0] = 0.f;
}

// ---------------- main: argmin + quantize + enc_idx + histogram + loss ----------------
// __launch_bounds__(256,2): 256-VGPR budget so x[64] stays in VGPRs (round-1 had
// VGPR_Count=48 -> x[] was exiled to AGPRs, one v_accvgpr_read per FMA operand).
// Occupancy is grid-limited (~3.4 waves/SIMD) anyway, so the budget costs nothing.
__global__ __launch_bounds__(256, 2) void vq_argmin(
    const float* __restrict__ in, const float* __restrict__ emb,
    const float* __restrict__ en2, float* __restrict__ qout,
    float* __restrict__ encout, float* __restrict__ hist,
    float* __restrict__ loss)
{
    __shared__ float lhist[KCODES];
    int tid = threadIdx.x;
    lhist[tid] = 0.f;
    __syncthreads();

    int n = blockIdx.x * 256 + tid;           // 864 blocks * 256 = NPOS exactly
    int b = (n >= SPA) ? 1 : 0;               // B = 2
    int s = n - b * SPA;
    const float* xp = in + b * (CCH * SPA) + s;

    float x[CCH];
#pragma unroll
    for (int c = 0; c < CCH; ++c) x[c] = xp[c * SPA];

    float x2 = 0.f;
    {
        float b0 = 0.f, b1 = 0.f, b2 = 0.f, b3 = 0.f;
#pragma unroll
        for (int c = 0; c < CCH; c += 4) {
            b0 = fmaf(x[c + 0], x[c + 0], b0);
            b1 = fmaf(x[c + 1], x[c + 1], b1);
            b2 = fmaf(x[c + 2], x[c + 2], b2);
            b3 = fmaf(x[c + 3], x[c + 3], b3);
        }
        x2 = (b0 + b1) + (b2 + b3);
    }

    float bestd = 3.402823466e38f;
    int bestk = 0;
#pragma unroll 2
    for (int k = 0; k < KCODES; ++k) {
        const float* e = emb + (k << 6);      // wave-uniform -> s_load rows
        float a0 = 0.f, a1 = 0.f, a2 = 0.f, a3 = 0.f;
#pragma unroll
        for (int c = 0; c < CCH; c += 4) {
            a0 = fmaf(x[c + 0], e[c + 0], a0);
            a1 = fmaf(x[c + 1], e[c + 1], a1);
            a2 = fmaf(x[c + 2], e[c + 2], a2);
            a3 = fmaf(x[c + 3], e[c + 3], a3);
        }
        float dot = (a0 + a1) + (a2 + a3);
        float dist = (x2 + en2[k]) - 2.f * dot;
        if (dist < bestd) { bestd = dist; bestk = k; }   // strict < keeps first min
    }

    atomicAdd(&lhist[bestk], 1.0f);

    const float* eb = emb + (bestk << 6);     // per-lane gather, table L1/L2-hot
    float* qp = qout + b * (CCH * SPA) + s;
    float lsum = 0.f;
#pragma unroll
    for (int c = 0; c < CCH; ++c) {
        float q = eb[c];
        float d = q - x[c];
        lsum = fmaf(d, d, lsum);
        qp[c * SPA] = q;
    }
    encout[n] = (float)bestk;

    for (int off = 32; off > 0; off >>= 1) lsum += __shfl_down(lsum, off, 64);
    if ((tid & 63) == 0)
        unsafeAtomicAdd(loss, lsum * (2.5f / 14155776.f));

    __syncthreads();
    unsafeAtomicAdd(&hist[tid], lhist[tid]);
}

// ---------------- dw: per-block LDS accumulate -> private partial buffer ----------------
// LDS layout [c][k ^ (c&31)]: 64KB exactly, conflict-reduced in both phases.
// No global atomics: block bid writes partial[bid] (64KB), reduced afterwards.
__global__ __launch_bounds__(DWTHR) void vq_dw_part(
    const float* __restrict__ in, const float* __restrict__ encout,
    float* __restrict__ partial)
{
    __shared__ float l[CCH * KCODES];
    int tid = threadIdx.x;
    for (int i = tid; i < CCH * KCODES; i += DWTHR) l[i] = 0.f;
    __syncthreads();

    int n = blockIdx.x * DWTHR + tid;         // exactly NPOS threads
    int b = (n >= SPA) ? 1 : 0;
    int s = n - b * SPA;
    int k = (int)encout[n];
    const float* xp = in + b * (CCH * SPA) + s;
#pragma unroll
    for (int c = 0; c < CCH; ++c)
        atomicAdd(&l[(c << 8) + (k ^ (c & 31))], xp[c * SPA]);
    __syncthreads();

    float* pp = partial + (size_t)blockIdx.x * (CCH * KCODES);
    for (int i = tid; i < CCH * KCODES; i += DWTHR) {
        int k2 = i >> 6, c = i & 63;          // i = k*64 + c -> coalesced stores
        pp[i] = l[(c << 8) + (k2 ^ (c & 31))];
    }
}

__global__ __launch_bounds__(256) void vq_dw_reduce(
    const float* __restrict__ partial, float* __restrict__ dw)
{
    int i = blockIdx.x * 256 + threadIdx.x;   // 64 blocks -> 16384 threads
    float s0 = 0.f, s1 = 0.f, s2 = 0.f, s3 = 0.f;
#pragma unroll 4
    for (int p = 0; p < DWBLK; p += 4) {
        s0 += partial[(size_t)(p + 0) * (CCH * KCODES) + i];
        s1 += partial[(size_t)(p + 1) * (CCH * KCODES) + i];
        s2 += partial[(size_t)(p + 2) * (CCH * KCODES) + i];
        s3 += partial[(size_t)(p + 3) * (CCH * KCODES) + i];
    }
    dw[i] = (s0 + s1) + (s2 + s3);
}

// ---------------- atomic fallback (only if ws too small for partials) ----------------
__global__ __launch_bounds__(DWTHR) void vq_dw_atomic(
    const float* __restrict__ in, const float* __restrict__ encout,
    float* __restrict__ dw)
{
    __shared__ float l[CCH * KCODES];
    int tid = threadIdx.x;
    for (int i = tid; i < CCH * KCODES; i += DWTHR) l[i] = 0.f;
    __syncthreads();
    int n = blockIdx.x * DWTHR + tid;
    int b = (n >= SPA) ? 1 : 0;
    int s = n - b * SPA;
    int k = (int)encout[n];
    const float* xp = in + b * (CCH * SPA) + s;
#pragma unroll
    for (int c = 0; c < CCH; ++c)
        atomicAdd(&l[(c << 8) + (k ^ (c & 31))], xp[c * SPA]);
    __syncthreads();
    for (int i = tid; i < CCH * KCODES; i += DWTHR) {
        int k2 = i >> 6, c = i & 63;
        unsafeAtomicAdd(&dw[i], l[(c << 8) + (k2 ^ (c & 31))]);
    }
}

// ---------------- EMA finalize ----------------
__global__ __launch_bounds__(256) void vq_ema(
    const float* __restrict__ csize, const float* __restrict__ emaw,
    const float* __restrict__ hist, const float* __restrict__ dw,
    float* __restrict__ embo)
{
    __shared__ float red[KCODES];
    int t = threadIdx.x;
    float ncs = 0.99f * csize[t] + 0.01f * hist[t];
    red[t] = ncs;
    __syncthreads();
    for (int off = 128; off > 0; off >>= 1) {
        if (t < off) red[t] += red[t + off];
        __syncthreads();
    }
    float nsum = red[0];
    float w = (ncs + 1e-5f) / (nsum + 256.f * 1e-5f) * nsum;
#pragma unroll
    for (int c = 0; c < CCH; ++c) {
        int i = (t << 6) + c;
        float nw = 0.99f * emaw[i] + 0.01f * dw[i];
        embo[i] = nw / w;
    }
}

extern "C" void kernel_launch(void* const* d_in, const int* in_sizes, int n_in,
                              void* d_out, int out_size, void* d_ws, size_t ws_size,
                              hipStream_t stream)
{
    const float* in   = (const float*)d_in[0];
    const float* emb  = (const float*)d_in[1];
    const float* cs   = (const float*)d_in[2];
    const float* emaw = (const float*)d_in[3];

    float* out  = (float*)d_out;
    float* qout = out;                         // 14,155,776
    float* loss = out + NELEM;                 // 1
    float* enc  = loss + 1;                    // 221,184
    float* hist = enc + NPOS;                  // 256  (== encodings_sum output)
    float* embo = hist + KCODES;               // 16,384

    float* en2     = (float*)d_ws;             // 256
    float* dw      = en2 + KCODES;             // 16,384
    float* partial = dw + CCH * KCODES;        // 432 * 16,384

    size_t need = (size_t)(KCODES + CCH * KCODES) * 4
                + (size_t)DWBLK * CCH * KCODES * 4;
    bool use_part = (ws_size >= need);         // ws_size constant per session -> graph-safe

    vq_init<<<dim3(64), dim3(256), 0, stream>>>(emb, en2, dw, hist, loss);
    vq_argmin<<<dim3(864), dim3(256), 0, stream>>>(in, emb, en2, qout, enc, hist, loss);
    if (use_part) {
        vq_dw_part<<<dim3(DWBLK), dim3(DWTHR), 0, stream>>>(in, enc, partial);
        vq_dw_reduce<<<dim3(64), dim3(256), 0, stream>>>(partial, dw);
    } else {
        vq_dw_atomic<<<dim3(DWBLK), dim3(DWTHR), 0, stream>>>(in, enc, dw);
    }
    vq_ema<<<dim3(1), dim3(256), 0, stream>>>(cs, emaw, hist, dw, embo);
}

// Round 5
// 268.095 us; speedup vs baseline: 1.4805x; 1.4805x over previous
//
#include <hip/hip_runtime.h>
#include <hip/hip_bf16.h>

#define SPA 110592            // D*H*W = 48*48*48
#define NPOS 221184           // B * SPA  (B=2)
#define NELEM 14155776        // B*C*SPA
#define KCODES 256
#define CCH 64
#define DWBLK 432             // 432 * 512 = NPOS
#define DWTHR 512
#define EPS_TIE 0.0625f

typedef __attribute__((ext_vector_type(8))) short bf16x8;   // 8 bf16 = 4 VGPRs
typedef __attribute__((ext_vector_type(16))) float f32x16;  // MFMA 32x32 accum

// split fp32 -> bf16 hi (truncate) + bf16 lo (truncate of residual); err ~2^-16|x|
__device__ __forceinline__ void bf16split(float v, short& h, short& l) {
    unsigned bits = __builtin_bit_cast(unsigned, v);
    h = (short)(bits >> 16);
    float hf = __builtin_bit_cast(float, bits & 0xFFFF0000u);
    float res = v - hf;
    l = (short)(__builtin_bit_cast(unsigned, res) >> 16);
}

// ---------------- init: zero accumulators, precompute ||e_k||^2 ----------------
__global__ __launch_bounds__(256) void vq_init(
    const float* __restrict__ emb, float* __restrict__ en2,
    float* __restrict__ dw, float* __restrict__ hist, float* __restrict__ loss)
{
    int t = blockIdx.x * 256 + threadIdx.x;   // 64 blocks
    if (t < CCH * KCODES) dw[t] = 0.f;        // needed by atomic fallback only
    if (t < KCODES) {
        const float* e = emb + (t << 6);
        float s = 0.f;
#pragma unroll
        for (int c = 0; c < CCH; ++c) s = fmaf(e[c], e[c], s);
        en2[t] = s;
        hist[t] = 0.f;
    }
    if (t == 0) loss[0] = 0.f;
}

// ---------------- MFMA argmin: D~[k,p] = e2[k] - 2*(eh+el).(xh+xl) ----------------
// Block: 256 thr (4 waves), 128 positions. Wave w owns codes [w*64, w*64+64) as two
// 32-code A-tiles resident in registers; B = x fragments from LDS. Per position we
// keep approx top-2 over 256 codes; near-ties (<=EPS_TIE) rescored exactly in fp32.
__global__ __launch_bounds__(256, 2) void vq_argmin_mfma(
    const float* __restrict__ in, const float* __restrict__ emb,
    const float* __restrict__ en2, float* __restrict__ qout,
    float* __restrict__ encout, float* __restrict__ hist,
    float* __restrict__ loss)
{
    // LDS: x bf16 hi/lo grouped by 8-channel octets -> conflict-free ds_read_b128
    __shared__ __align__(16) short xh[8][128][8];
    __shared__ __align__(16) short xl[8][128][8];
    __shared__ float e2s[KCODES];
    __shared__ float pm1[4][128], pm2[4][128];
    __shared__ int   pk1[4][128], pk2[4][128];
    __shared__ int   bestkS[128];
    __shared__ float lhist[KCODES];
    __shared__ float lred[4];

    int tid  = threadIdx.x;
    int w    = tid >> 6, lane = tid & 63;
    int hi   = lane >> 5, col = lane & 31;
    int wbase = w * 64;

    int blk = blockIdx.x;                 // 1728 blocks; 864 per batch
    int b   = (blk >= 864) ? 1 : 0;
    int s0  = (blk - b * 864) * 128;
    const float* xbase = in + b * (CCH * SPA) + s0;

    if (tid < KCODES) { e2s[tid] = en2[tid]; lhist[tid] = 0.f; }

    // --- resident A fragments: codes as M-rows. lane: row=col, k=hi*8+jj ---
    bf16x8 Ah[2][4], Al[2][4];
#pragma unroll
    for (int ct = 0; ct < 2; ++ct) {
        int code = wbase + ct * 32 + col;
        const float* er = emb + (code << 6) + hi * 8;
#pragma unroll
        for (int j = 0; j < 4; ++j) {
            bf16x8 hfr, lfr;
#pragma unroll
            for (int jj = 0; jj < 8; ++jj) {
                short hs, ls; bf16split(er[j * 16 + jj], hs, ls);
                hfr[jj] = hs; lfr[jj] = ls;
            }
            Ah[ct][j] = hfr; Al[ct][j] = lfr;
        }
    }

    // --- stage x -> LDS bf16 hi/lo; [g= c>>3][p][c&7], coalesced reads+writes ---
    {
        int tg = tid >> 7, p = tid & 127;
        const float* xb = xbase + p;
#pragma unroll
        for (int cb = 0; cb < 4; ++cb) {
            int c0 = tg * 32 + cb * 8;
            bf16x8 hfr, lfr;
#pragma unroll
            for (int jj = 0; jj < 8; ++jj) {
                short hs, ls; bf16split(xb[(c0 + jj) * SPA], hs, ls);
                hfr[jj] = hs; lfr[jj] = ls;
            }
            *(bf16x8*)&xh[c0 >> 3][p][0] = hfr;
            *(bf16x8*)&xl[c0 >> 3][p][0] = lfr;
        }
    }
    __syncthreads();

    // --- main MFMA + per-position top-2 ---
#pragma unroll 1
    for (int pt = 0; pt < 4; ++pt) {
        int pos = pt * 32 + col;
        f32x16 c0, c1;
#pragma unroll
        for (int i = 0; i < 16; ++i) { c0[i] = 0.f; c1[i] = 0.f; }

#pragma unroll
        for (int j = 0; j < 4; ++j) {
            bf16x8 bh = *(const bf16x8*)&xh[j * 2 + hi][pos][0];
            bf16x8 bl = *(const bf16x8*)&xl[j * 2 + hi][pos][0];
            c0 = __builtin_amdgcn_mfma_f32_32x32x16_bf16(Ah[0][j], bh, c0, 0, 0, 0);
            c1 = __builtin_amdgcn_mfma_f32_32x32x16_bf16(Ah[1][j], bh, c1, 0, 0, 0);
            c0 = __builtin_amdgcn_mfma_f32_32x32x16_bf16(Ah[0][j], bl, c0, 0, 0, 0);
            c1 = __builtin_amdgcn_mfma_f32_32x32x16_bf16(Ah[1][j], bl, c1, 0, 0, 0);
            c0 = __builtin_amdgcn_mfma_f32_32x32x16_bf16(Al[0][j], bh, c0, 0, 0, 0);
            c1 = __builtin_amdgcn_mfma_f32_32x32x16_bf16(Al[1][j], bh, c1, 0, 0, 0);
        }

        // top-2 within lane. C/D map: col=lane&31, row=(r&3)+8*(r>>2)+4*hi  [m74/m101]
        float m1 = 1e30f, m2 = 1e30f; int k1 = 0, k2 = 0;
#pragma unroll
        for (int ct = 0; ct < 2; ++ct) {
#pragma unroll
            for (int r = 0; r < 16; ++r) {
                int kc  = wbase + ct * 32 + (r & 3) + 8 * (r >> 2) + 4 * hi;
                float d = fmaf(-2.f, (ct ? c1[r] : c0[r]), e2s[kc]);
                bool lt1 = d < m1, lt2 = d < m2;
                float nm2 = lt1 ? m1 : (lt2 ? d : m2);
                int   nk2 = lt1 ? k1 : (lt2 ? kc : k2);
                m1 = lt1 ? d : m1; k1 = lt1 ? kc : k1;
                m2 = nm2; k2 = nk2;
            }
        }
        // merge with partner lane (hi^1) covering the other row half
        float om1 = __shfl_xor(m1, 32, 64), om2 = __shfl_xor(m2, 32, 64);
        int   ok1 = __shfl_xor(k1, 32, 64), ok2 = __shfl_xor(k2, 32, 64);
        if (om1 < m1) {
            float t2 = (m1 < om2) ? m1 : om2;
            int   tk = (m1 < om2) ? k1 : ok2;
            m2 = t2; k2 = tk; m1 = om1; k1 = ok1;
        } else {
            float t2 = (om1 < m2) ? om1 : m2;
            int   tk = (om1 < m2) ? ok1 : k2;
            m2 = t2; k2 = tk;
        }
        if (hi == 0) {
            pm1[w][pos] = m1; pk1[w][pos] = k1;
            pm2[w][pos] = m2; pk2[w][pos] = k2;
        }
    }
    __syncthreads();

    // --- combine 4 waves' top-2, rescore near-ties exactly in fp32 ---
    if (tid < 128) {
        int p = tid;
        float M1 = pm1[0][p], M2 = pm2[0][p];
        int   K1 = pk1[0][p], K2 = pk2[0][p];
#pragma unroll
        for (int ww = 1; ww < 4; ++ww) {
            float om1 = pm1[ww][p], om2 = pm2[ww][p];
            int   ok1 = pk1[ww][p], ok2 = pk2[ww][p];
            if (om1 < M1) {
                float t2 = (M1 < om2) ? M1 : om2;
                int   tk = (M1 < om2) ? K1 : ok2;
                M2 = t2; K2 = tk; M1 = om1; K1 = ok1;
            } else {
                float t2 = (om1 < M2) ? om1 : M2;
                int   tk = (om1 < M2) ? ok1 : K2;
                M2 = t2; K2 = tk;
            }
        }
        int bk = K1;
        if (M2 <= M1 + EPS_TIE) {      // rare (~1%): exact fp32 re-score, ref semantics
            int ka = min(K1, K2), kb = max(K1, K2);
            const float* xb2 = xbase + p;
            const float* ea  = emb + (ka << 6);
            const float* eb2 = emb + (kb << 6);
            float x2 = 0.f, da = 0.f, db = 0.f;
#pragma unroll 4
            for (int c = 0; c < CCH; ++c) {
                float xv = xb2[c * SPA];
                x2 = fmaf(xv, xv, x2);
                da = fmaf(xv, ea[c], da);
                db = fmaf(xv, eb2[c], db);
            }
            float Da = x2 + en2[ka] - 2.f * da;
            float Db = x2 + en2[kb] - 2.f * db;
            bk = (Db < Da) ? kb : ka;  // tie -> lower index (ka)
        }
        bestkS[p] = bk;
        encout[b * SPA + s0 + p] = (float)bk;
        atomicAdd(&lhist[bk], 1.0f);
    }
    __syncthreads();

    // --- quantize write + exact commitment loss ---
    {
        int tg = tid >> 7, p = tid & 127;
        int k = bestkS[p];
        const float* ee  = emb + (k << 6) + tg * 32;
        const float* xb3 = xbase + p;
        float* qp = qout + b * (CCH * SPA) + s0 + p;
        float lsum = 0.f;
#pragma unroll
        for (int c = 0; c < 32; ++c) {
            float q  = ee[c];
            float xv = xb3[(tg * 32 + c) * SPA];
            float d  = q - xv;
            lsum = fmaf(d, d, lsum);
            qp[(tg * 32 + c) * SPA] = q;
        }
        for (int off = 32; off > 0; off >>= 1) lsum += __shfl_down(lsum, off, 64);
        if (lane == 0) lred[w] = lsum;
    }
    __syncthreads();
    if (tid == 0)
        unsafeAtomicAdd(loss, (lred[0] + lred[1] + lred[2] + lred[3]) * (2.5f / 14155776.f));
    if (tid < KCODES && lhist[tid] != 0.f)
        unsafeAtomicAdd(&hist[tid], lhist[tid]);
}

// ---------------- dw: per-block LDS accumulate -> private partial buffer ----------------
__global__ __launch_bounds__(DWTHR) void vq_dw_part(
    const float* __restrict__ in, const float* __restrict__ encout,
    float* __restrict__ partial)
{
    __shared__ float l[CCH * KCODES];
    int tid = threadIdx.x;
    for (int i = tid; i < CCH * KCODES; i += DWTHR) l[i] = 0.f;
    __syncthreads();

    int n = blockIdx.x * DWTHR + tid;
    int b = (n >= SPA) ? 1 : 0;
    int s = n - b * SPA;
    int k = (int)encout[n];
    const float* xp = in + b * (CCH * SPA) + s;
#pragma unroll
    for (int c = 0; c < CCH; ++c)
        atomicAdd(&l[(c << 8) + (k ^ (c & 31))], xp[c * SPA]);
    __syncthreads();

    float* pp = partial + (size_t)blockIdx.x * (CCH * KCODES);
    for (int i = tid; i < CCH * KCODES; i += DWTHR) {
        int k2 = i >> 6, c = i & 63;
        pp[i] = l[(c << 8) + (k2 ^ (c & 31))];
    }
}

__global__ __launch_bounds__(256) void vq_dw_reduce(
    const float* __restrict__ partial, float* __restrict__ dw)
{
    __shared__ float acc[4][64];
    int t = threadIdx.x, lane6 = t & 63, tsub = t >> 6;
    int i = blockIdx.x * 64 + lane6;          // 256 blocks x 64 outputs
    float s = 0.f;
    for (int p = tsub * 108; p < tsub * 108 + 108; ++p)
        s += partial[(size_t)p * (CCH * KCODES) + i];
    acc[tsub][lane6] = s;
    __syncthreads();
    if (tsub == 0)
        dw[i] = (acc[0][lane6] + acc[1][lane6]) + (acc[2][lane6] + acc[3][lane6]);
}

// ---------------- atomic fallback (only if ws too small for partials) ----------------
__global__ __launch_bounds__(DWTHR) void vq_dw_atomic(
    const float* __restrict__ in, const float* __restrict__ encout,
    float* __restrict__ dw)
{
    __shared__ float l[CCH * KCODES];
    int tid = threadIdx.x;
    for (int i = tid; i < CCH * KCODES; i += DWTHR) l[i] = 0.f;
    __syncthreads();
    int n = blockIdx.x * DWTHR + tid;
    int b = (n >= SPA) ? 1 : 0;
    int s = n - b * SPA;
    int k = (int)encout[n];
    const float* xp = in + b * (CCH * SPA) + s;
#pragma unroll
    for (int c = 0; c < CCH; ++c)
        atomicAdd(&l[(c << 8) + (k ^ (c & 31))], xp[c * SPA]);
    __syncthreads();
    for (int i = tid; i < CCH * KCODES; i += DWTHR) {
        int k2 = i >> 6, c = i & 63;
        unsafeAtomicAdd(&dw[i], l[(c << 8) + (k2 ^ (c & 31))]);
    }
}

// ---------------- EMA: weights (1 block), then parallel divide ----------------
__global__ __launch_bounds__(256) void vq_ema_w(
    const float* __restrict__ csize, const float* __restrict__ hist,
    float* __restrict__ wbuf)
{
    __shared__ float red[KCODES];
    int t = threadIdx.x;
    float ncs = 0.99f * csize[t] + 0.01f * hist[t];
    red[t] = ncs;
    __syncthreads();
    for (int off = 128; off > 0; off >>= 1) {
        if (t < off) red[t] += red[t + off];
        __syncthreads();
    }
    float nsum = red[0];
    wbuf[t] = (ncs + 1e-5f) / (nsum + 256.f * 1e-5f) * nsum;
}

__global__ __launch_bounds__(256) void vq_emb(
    const float* __restrict__ emaw, const float* __restrict__ dw,
    const float* __restrict__ wbuf, float* __restrict__ embo)
{
    int i = blockIdx.x * 256 + threadIdx.x;   // 64 blocks
    float nw = fmaf(0.01f, dw[i], 0.99f * emaw[i]);
    embo[i] = nw / wbuf[i >> 6];
}

extern "C" void kernel_launch(void* const* d_in, const int* in_sizes, int n_in,
                              void* d_out, int out_size, void* d_ws, size_t ws_size,
                              hipStream_t stream)
{
    const float* in   = (const float*)d_in[0];
    const float* emb  = (const float*)d_in[1];
    const float* cs   = (const float*)d_in[2];
    const float* emaw = (const float*)d_in[3];

    float* out  = (float*)d_out;
    float* qout = out;                         // 14,155,776
    float* loss = out + NELEM;                 // 1
    float* enc  = loss + 1;                    // 221,184
    float* hist = enc + NPOS;                  // 256  (encodings_sum output)
    float* embo = hist + KCODES;               // 16,384

    float* en2     = (float*)d_ws;             // 256
    float* wbuf    = en2 + KCODES;             // 256
    float* dw      = wbuf + KCODES;            // 16,384
    float* partial = dw + CCH * KCODES;        // 432 * 16,384

    size_t need = (size_t)(2 * KCODES + CCH * KCODES) * 4
                + (size_t)DWBLK * CCH * KCODES * 4;
    bool use_part = (ws_size >= need);         // constant per session -> graph-safe

    vq_init<<<dim3(64), dim3(256), 0, stream>>>(emb, en2, dw, hist, loss);
    vq_argmin_mfma<<<dim3(1728), dim3(256), 0, stream>>>(in, emb, en2, qout, enc, hist, loss);
    if (use_part) {
        vq_dw_part<<<dim3(DWBLK), dim3(DWTHR), 0, stream>>>(in, enc, partial);
        vq_dw_reduce<<<dim3(256), dim3(256), 0, stream>>>(partial, dw);
    } else {
        vq_dw_atomic<<<dim3(DWBLK), dim3(DWTHR), 0, stream>>>(in, enc, dw);
    }
    vq_ema_w<<<dim3(1), dim3(256), 0, stream>>>(cs, hist, wbuf);
    vq_emb<<<dim3(64), dim3(256), 0, stream>>>(emaw, dw, wbuf, embo);
}